// Round 8
// baseline (526.925 us; speedup 1.0000x reference)
//
#include <hip/hip_runtime.h>
#include <math.h>
#include <stdint.h>

#define NI 100000   // N_ITEMS
#define NB 512      // batch
#define NH 256      // hidden H
#define H3 768      // 3*H

typedef _Float16 f16x8 __attribute__((ext_vector_type(8)));
typedef _Float16 f16x4 __attribute__((ext_vector_type(4)));
typedef float    f32x4 __attribute__((ext_vector_type(4)));

__device__ __forceinline__ float tanh_fast(float x) {
    x = fminf(fmaxf(x, -9.0f), 9.0f);
    const float e = __expf(2.0f * x);
    return (e - 1.0f) * __builtin_amdgcn_rcpf(e + 1.0f);
}

// ---------------- GRU gate elementwise (layer 0: gather x_proj inline) ----------------
__global__ void k_gates0(const int* __restrict__ idx,
                         const float* __restrict__ Wih0,   // (768, NI)
                         const float* __restrict__ bih0,   // (768)
                         const float* __restrict__ hp,     // (512,768)
                         const float* __restrict__ hprev,  // (512,256)
                         float* __restrict__ hnew)         // (512,256)
{
    const int b = blockIdx.x;
    const int j = threadIdx.x;          // 0..255
    const int ib = idx[b];
    const float xr = Wih0[(size_t)(j          ) * NI + ib] + bih0[j];
    const float xz = Wih0[(size_t)(j + NH     ) * NI + ib] + bih0[j + NH];
    const float xn = Wih0[(size_t)(j + 2 * NH ) * NI + ib] + bih0[j + 2 * NH];
    const float hr = hp[b * H3 + j];
    const float hz = hp[b * H3 + NH + j];
    const float hn = hp[b * H3 + 2 * NH + j];
    const float h  = hprev[b * NH + j];
    const float r = 1.0f / (1.0f + expf(-(xr + hr)));
    const float z = 1.0f / (1.0f + expf(-(xz + hz)));
    const float n = tanhf(xn + r * hn);
    hnew[b * NH + j] = (1.0f - z) * n + z * h;
}

// ---------------- GRU gate elementwise (layer 1) ----------------
__global__ void k_gates(const float* __restrict__ xp,
                        const float* __restrict__ hp,
                        const float* __restrict__ hprev,
                        float* __restrict__ hnew)
{
    const int b = blockIdx.x;
    const int j = threadIdx.x;
    const float xr = xp[b * H3 + j];
    const float xz = xp[b * H3 + NH + j];
    const float xn = xp[b * H3 + 2 * NH + j];
    const float hr = hp[b * H3 + j];
    const float hz = hp[b * H3 + NH + j];
    const float hn = hp[b * H3 + 2 * NH + j];
    const float h  = hprev[b * NH + j];
    const float r = 1.0f / (1.0f + expf(-(xr + hr)));
    const float z = 1.0f / (1.0f + expf(-(xz + hz)));
    const float n = tanhf(xn + r * hn);
    hnew[b * NH + j] = (1.0f - z) * n + z * h;
}

// ---------------- layer 2 gates: also emit fp16 copy of h2 for the MFMA GEMM --------
__global__ void k_gates_last(const float* __restrict__ xp,
                             const float* __restrict__ hp,
                             const float* __restrict__ hprev,
                             float* __restrict__ hnew,
                             _Float16* __restrict__ Xh)    // (512,256) fp16
{
    const int b = blockIdx.x;
    const int j = threadIdx.x;
    const float xr = xp[b * H3 + j];
    const float xz = xp[b * H3 + NH + j];
    const float xn = xp[b * H3 + 2 * NH + j];
    const float hr = hp[b * H3 + j];
    const float hz = hp[b * H3 + NH + j];
    const float hn = hp[b * H3 + 2 * NH + j];
    const float h  = hprev[b * NH + j];
    const float r = 1.0f / (1.0f + expf(-(xr + hr)));
    const float z = 1.0f / (1.0f + expf(-(xz + hz)));
    const float n = tanhf(xn + r * hn);
    const float v = (1.0f - z) * n + z * h;
    hnew[b * NH + j] = v;
    Xh[b * NH + j] = (_Float16)v;
}

// ---------------- small tiled fp32 GEMM:  C = A @ B.T + bias (z-batched) ----------------
__global__ __launch_bounds__(256)
void k_gemm_small(const float* __restrict__ A0,
                  const float* __restrict__ B0,
                  const float* __restrict__ bias0,
                  float* __restrict__ C0,
                  int M, int N, int K,
                  int sA, int sB, int sBias, int sC)
{
    constexpr int BM = 64, BN = 64, BK = 32;
    __shared__ float As[BK][BM];
    __shared__ float Bs[BK][BN];

    const float* A    = A0 + (size_t)blockIdx.z * sA;
    const float* Bm   = B0 + (size_t)blockIdx.z * sB;
    const float* bias = bias0 + (size_t)blockIdx.z * sBias;
    float*       C    = C0 + (size_t)blockIdx.z * sC;

    const int tid = threadIdx.x;
    const int tx  = tid & 15;
    const int ty  = tid >> 4;
    const int m0  = blockIdx.x * BM;
    const int n0  = blockIdx.y * BN;

    float acc[4][4];
#pragma unroll
    for (int i = 0; i < 4; i++)
#pragma unroll
        for (int j = 0; j < 4; j++) acc[i][j] = 0.0f;

    for (int k0 = 0; k0 < K; k0 += BK) {
#pragma unroll
        for (int f = 0; f < 2; f++) {
            const int fid = tid + f * 256;
            const int row = fid >> 3;
            const int t4  = fid & 7;
            const int mp  = row ^ ((t4 & 3) << 3);
            {
                const float4 v = *(const float4*)(A + (size_t)(m0 + row) * K + k0 + t4 * 4);
                As[t4 * 4 + 0][mp] = v.x; As[t4 * 4 + 1][mp] = v.y;
                As[t4 * 4 + 2][mp] = v.z; As[t4 * 4 + 3][mp] = v.w;
            }
            {
                const float4 v = *(const float4*)(Bm + (size_t)(n0 + row) * K + k0 + t4 * 4);
                Bs[t4 * 4 + 0][mp] = v.x; Bs[t4 * 4 + 1][mp] = v.y;
                Bs[t4 * 4 + 2][mp] = v.z; Bs[t4 * 4 + 3][mp] = v.w;
            }
        }
        __syncthreads();
#pragma unroll
        for (int kk = 0; kk < BK; kk++) {
            const int s = ((kk >> 2) & 3) << 3;
            const float4 a0 = *(const float4*)&As[kk][(ty * 4) ^ s];
            const float4 b0 = *(const float4*)&Bs[kk][(tx * 4) ^ s];
            const float av[4] = {a0.x, a0.y, a0.z, a0.w};
            const float bv[4] = {b0.x, b0.y, b0.z, b0.w};
#pragma unroll
            for (int i = 0; i < 4; i++)
#pragma unroll
                for (int j = 0; j < 4; j++)
                    acc[i][j] = fmaf(av[i], bv[j], acc[i][j]);
        }
        __syncthreads();
    }

#pragma unroll
    for (int i = 0; i < 4; i++) {
        const size_t rowoff = (size_t)(m0 + ty * 4 + i) * N;
        const int gn = n0 + tx * 4;
        const float4 bb = *(const float4*)(bias + gn);
        float4 v;
        v.x = acc[i][0] + bb.x; v.y = acc[i][1] + bb.y;
        v.z = acc[i][2] + bb.z; v.w = acc[i][3] + bb.w;
        *(float4*)(C + rowoff + gn) = v;
    }
}

// ---------------- output projection: act = tanh(x @ Wout.T + bout), fp16 MFMA ----------
// BM=512 (whole batch), BN=64 -> W row fetched from HBM exactly once. 512 thr = 8 waves,
// wave w owns m rows [w*64, w*64+64). W panel staged as FP16 in 32 KB LDS (reg-stage:
// coalesced 1KB-row fp32 loads -> cvt once -> swizzled ds_write_b64), so the K-loop is
// pure {4 ds_read_b128 + 4 X-loads + 16 MFMA} per step with ZERO cvt and no barriers.
// 32 KB LDS + 8 waves -> 4 blocks/CU: staggered blocks overlap read/compute/write.
// Swizzle: 16B slot s of row r at phys (s&24)|((s^r)&7) — same XOR on write and read.
// mfma(A=W, B=X): D row((lane>>4)*4+reg)=n, col(lane&15)=m (verified r1-r7 layout).
// Epilogue: 4 passes x 128 rows through the same LDS -> 256B-contiguous C stores.
__global__ __launch_bounds__(512, 8)
void k_out_mfma(const _Float16* __restrict__ Xh,  // (512,256) fp16
                const float* __restrict__ W,      // (NI,256) fp32
                const float* __restrict__ bout,   // (NI)
                float* __restrict__ C)            // (512,NI)
{
    __shared__ __align__(16) _Float16 S16[64 * 256];   // 32 KB W panel, reused for C
    float* Cs = (float*)S16;                           // (128 rows x 64 cols) fp32

    const int n0   = blockIdx.x * 64;          // n-tile base (1563 tiles)
    const int tid  = threadIdx.x;
    const int w    = tid >> 6;                 // wave 0..7 -> m rows [w*64, w*64+64)
    const int lane = tid & 63;
    const int lr   = lane & 15;
    const int lg   = lane >> 4;                // 0..3

    // ---- stage: 64 rows x 1KB fp32 (coalesced, one row per wave-instr) -> fp16 LDS ----
    float4 stg[8];
#pragma unroll
    for (int it = 0; it < 8; ++it) {
        const int fid = it * 512 + tid;        // fp32 16B-chunk id, 0..4095
        const int row = fid >> 6;              // 0..63
        const int c32 = fid & 63;
        int gr = n0 + row; if (gr >= NI) gr = NI - 1;
        stg[it] = *(const float4*)(W + (size_t)gr * NH + c32 * 4);
    }
#pragma unroll
    for (int it = 0; it < 8; ++it) {
        const int fid = it * 512 + tid;
        const int row = fid >> 6;
        const int c32 = fid & 63;
        const int s   = c32 >> 1;                       // 16B fp16 slot 0..31
        const int ps  = (s & 24) | ((s ^ row) & 7);     // XOR swizzle
        f16x4 h;
        h[0] = (_Float16)stg[it].x; h[1] = (_Float16)stg[it].y;
        h[2] = (_Float16)stg[it].z; h[3] = (_Float16)stg[it].w;
        *(f16x4*)((char*)S16 + row * 512 + ps * 16 + (c32 & 1) * 8) = h;
    }

    f32x4 acc[4][4];
#pragma unroll
    for (int nf = 0; nf < 4; ++nf)
#pragma unroll
        for (int mf = 0; mf < 4; ++mf) acc[nf][mf] = (f32x4){0.f, 0.f, 0.f, 0.f};

    __syncthreads();

    const _Float16* xbase = Xh + (size_t)(w * 64 + lr) * NH + lg * 8;

    // ---- K-loop: 8 steps, no barriers, no cvt ----
#pragma unroll
    for (int t = 0; t < 8; ++t) {
        f16x8 xf[4];
#pragma unroll
        for (int mf = 0; mf < 4; ++mf)
            xf[mf] = *(const f16x8*)(xbase + mf * 16 * NH + t * 32);
#pragma unroll
        for (int nf = 0; nf < 4; ++nf) {
            const int rl = nf * 16 + lr;                    // W-panel row 0..63
            const int s  = t * 4 + lg;                      // 16B slot 0..31
            const int ps = (s & 24) | ((s ^ rl) & 7);
            const f16x8 wf = *(const f16x8*)((const char*)S16 + rl * 512 + ps * 16);
#pragma unroll
            for (int mf = 0; mf < 4; ++mf)
                acc[nf][mf] = __builtin_amdgcn_mfma_f32_16x16x32_f16(
                    wf, xf[mf], acc[nf][mf], 0, 0, 0);
        }
    }

    // ---- epilogue: 4 passes x 128 rows via LDS; 256B-contiguous global stores ----
    __syncthreads();                            // all K-loop LDS reads done
    const int myp = w >> 1;                     // pass owning this wave's rows
#pragma unroll
    for (int p = 0; p < 4; ++p) {
        if (p) __syncthreads();                 // prev pass reads done
        if (myp == p) {
#pragma unroll
            for (int nf = 0; nf < 4; ++nf) {
                const int gn = n0 + nf * 16 + lg * 4;
                const float4 bb = (gn < NI) ? *(const float4*)(bout + gn)
                                            : make_float4(0.f, 0.f, 0.f, 0.f);
#pragma unroll
                for (int mf = 0; mf < 4; ++mf) {
                    const int lrow = (w & 1) * 64 + mf * 16 + lr;   // 0..127
                    const int q    = nf * 4 + lg;                   // float4 slot 0..15
                    const int pq   = (q & 8) | ((q ^ lrow) & 7);
                    float4 v;
                    v.x = tanh_fast(acc[nf][mf][0] + bb.x);
                    v.y = tanh_fast(acc[nf][mf][1] + bb.y);
                    v.z = tanh_fast(acc[nf][mf][2] + bb.z);
                    v.w = tanh_fast(acc[nf][mf][3] + bb.w);
                    *(float4*)(Cs + lrow * 64 + pq * 4) = v;
                }
            }
        }
        __syncthreads();
#pragma unroll
        for (int it = 0; it < 4; ++it) {
            const int fid = it * 512 + tid;     // 0..2047
            const int row = fid >> 4;           // 0..127
            const int q   = fid & 15;
            const int pq  = (q & 8) | ((q ^ row) & 7);
            const int gn  = n0 + q * 4;
            if (gn < NI) {
                const f32x4 v = *(const f32x4*)(Cs + row * 64 + pq * 4);
                *(f32x4*)(C + (size_t)(p * 128 + row) * NI + gn) = v;
            }
        }
    }
}

extern "C" void kernel_launch(void* const* d_in, const int* in_sizes, int n_in,
                              void* d_out, int out_size, void* d_ws, size_t ws_size,
                              hipStream_t stream)
{
    const int*   idx    = (const int*)  d_in[0];
    const float* hidden = (const float*)d_in[1];   // (3,512,256)
    const float* Wih0   = (const float*)d_in[2];   // (768,100000)
    const float* WihHi  = (const float*)d_in[3];   // (2,768,256)
    const float* Whh    = (const float*)d_in[4];   // (3,768,256)
    const float* bih    = (const float*)d_in[5];   // (3,768)
    const float* bhh    = (const float*)d_in[6];   // (3,768)
    const float* Wout   = (const float*)d_in[7];   // (100000,256)
    const float* bout   = (const float*)d_in[8];   // (100000)

    float* act  = (float*)d_out;                  // (512, NI)
    float* hnew = act + (size_t)NB * NI;          // (3,512,256)
    // fp32 scratch lives in the activation region; final GEMM overwrites it.
    float* hp = act;                              // (3,512,768)
    float* xp = act + 3 * NB * H3;                // (512,768)
    // fp16 X lives in d_ws (must survive while the big GEMM writes act)
    _Float16* Xh = (_Float16*)d_ws;               // (512,256) = 256 KB

    const dim3 bs(256);
    const dim3 gs_hp(NB / 64, H3 / 64, 3);
    const dim3 gs_xp(NB / 64, H3 / 64, 1);

    // ---- all hidden-projections (depend only on input `hidden`) ----
    k_gemm_small<<<gs_hp, bs, 0, stream>>>(hidden, Whh, bhh, hp,
                                           NB, H3, NH, NB * NH, H3 * NH, H3, NB * H3);
    // ---- layer 0 (x_proj gathered inline) ----
    k_gates0<<<NB, bs, 0, stream>>>(idx, Wih0, bih, hp, hidden, hnew);
    // ---- layer 1 ----
    k_gemm_small<<<gs_xp, bs, 0, stream>>>(hnew, WihHi, bih + H3, xp,
                                           NB, H3, NH, 0, 0, 0, 0);
    k_gates<<<NB, bs, 0, stream>>>(xp, hp + NB * H3, hidden + NB * NH, hnew + NB * NH);
    // ---- layer 2 (also emits fp16 h2) ----
    k_gemm_small<<<gs_xp, bs, 0, stream>>>(hnew + NB * NH, WihHi + H3 * NH, bih + 2 * H3, xp,
                                           NB, H3, NH, 0, 0, 0, 0);
    k_gates_last<<<NB, bs, 0, stream>>>(xp, hp + 2 * NB * H3, hidden + 2 * NB * NH,
                                        hnew + 2 * NB * NH, Xh);

    // ---- output projection: 1563 n-tiles of 64, whole batch per block ----
    k_out_mfma<<<dim3((NI + 63) / 64), dim3(512), 0, stream>>>(Xh, Wout, bout, act);
}

// Round 9
// 308.363 us; speedup vs baseline: 1.7088x; 1.7088x over previous
//
#include <hip/hip_runtime.h>
#include <math.h>
#include <stdint.h>

#define NI 100000   // N_ITEMS
#define NB 512      // batch
#define NH 256      // hidden H
#define H3 768      // 3*H
#define NT 1563     // ceil(NI/64) n-tiles
#define GRID_OUT 512

typedef _Float16 f16x8 __attribute__((ext_vector_type(8)));
typedef _Float16 f16x4 __attribute__((ext_vector_type(4)));
typedef float    f32x4 __attribute__((ext_vector_type(4)));

__device__ __forceinline__ float tanh_fast(float x) {
    x = fminf(fmaxf(x, -9.0f), 9.0f);
    const float e = __expf(2.0f * x);
    return (e - 1.0f) * __builtin_amdgcn_rcpf(e + 1.0f);
}

// ---------------- GRU gate elementwise (layer 0: gather x_proj inline) ----------------
__global__ void k_gates0(const int* __restrict__ idx,
                         const float* __restrict__ Wih0,   // (768, NI)
                         const float* __restrict__ bih0,   // (768)
                         const float* __restrict__ hp,     // (512,768)
                         const float* __restrict__ hprev,  // (512,256)
                         float* __restrict__ hnew)         // (512,256)
{
    const int b = blockIdx.x;
    const int j = threadIdx.x;          // 0..255
    const int ib = idx[b];
    const float xr = Wih0[(size_t)(j          ) * NI + ib] + bih0[j];
    const float xz = Wih0[(size_t)(j + NH     ) * NI + ib] + bih0[j + NH];
    const float xn = Wih0[(size_t)(j + 2 * NH ) * NI + ib] + bih0[j + 2 * NH];
    const float hr = hp[b * H3 + j];
    const float hz = hp[b * H3 + NH + j];
    const float hn = hp[b * H3 + 2 * NH + j];
    const float h  = hprev[b * NH + j];
    const float r = 1.0f / (1.0f + expf(-(xr + hr)));
    const float z = 1.0f / (1.0f + expf(-(xz + hz)));
    const float n = tanhf(xn + r * hn);
    hnew[b * NH + j] = (1.0f - z) * n + z * h;
}

// ---------------- GRU gate elementwise (layer 1) ----------------
__global__ void k_gates(const float* __restrict__ xp,
                        const float* __restrict__ hp,
                        const float* __restrict__ hprev,
                        float* __restrict__ hnew)
{
    const int b = blockIdx.x;
    const int j = threadIdx.x;
    const float xr = xp[b * H3 + j];
    const float xz = xp[b * H3 + NH + j];
    const float xn = xp[b * H3 + 2 * NH + j];
    const float hr = hp[b * H3 + j];
    const float hz = hp[b * H3 + NH + j];
    const float hn = hp[b * H3 + 2 * NH + j];
    const float h  = hprev[b * NH + j];
    const float r = 1.0f / (1.0f + expf(-(xr + hr)));
    const float z = 1.0f / (1.0f + expf(-(xz + hz)));
    const float n = tanhf(xn + r * hn);
    hnew[b * NH + j] = (1.0f - z) * n + z * h;
}

// ---------------- layer 2 gates: also emit fp16 copy of h2 for the MFMA GEMM --------
__global__ void k_gates_last(const float* __restrict__ xp,
                             const float* __restrict__ hp,
                             const float* __restrict__ hprev,
                             float* __restrict__ hnew,
                             _Float16* __restrict__ Xh)    // (512,256) fp16
{
    const int b = blockIdx.x;
    const int j = threadIdx.x;
    const float xr = xp[b * H3 + j];
    const float xz = xp[b * H3 + NH + j];
    const float xn = xp[b * H3 + 2 * NH + j];
    const float hr = hp[b * H3 + j];
    const float hz = hp[b * H3 + NH + j];
    const float hn = hp[b * H3 + 2 * NH + j];
    const float h  = hprev[b * NH + j];
    const float r = 1.0f / (1.0f + expf(-(xr + hr)));
    const float z = 1.0f / (1.0f + expf(-(xz + hz)));
    const float n = tanhf(xn + r * hn);
    const float v = (1.0f - z) * n + z * h;
    hnew[b * NH + j] = v;
    Xh[b * NH + j] = (_Float16)v;
}

// ---------------- small tiled fp32 GEMM:  C = A @ B.T + bias (z-batched) ----------------
__global__ __launch_bounds__(256)
void k_gemm_small(const float* __restrict__ A0,
                  const float* __restrict__ B0,
                  const float* __restrict__ bias0,
                  float* __restrict__ C0,
                  int M, int N, int K,
                  int sA, int sB, int sBias, int sC)
{
    constexpr int BM = 64, BN = 64, BK = 32;
    __shared__ float As[BK][BM];
    __shared__ float Bs[BK][BN];

    const float* A    = A0 + (size_t)blockIdx.z * sA;
    const float* Bm   = B0 + (size_t)blockIdx.z * sB;
    const float* bias = bias0 + (size_t)blockIdx.z * sBias;
    float*       C    = C0 + (size_t)blockIdx.z * sC;

    const int tid = threadIdx.x;
    const int tx  = tid & 15;
    const int ty  = tid >> 4;
    const int m0  = blockIdx.x * BM;
    const int n0  = blockIdx.y * BN;

    float acc[4][4];
#pragma unroll
    for (int i = 0; i < 4; i++)
#pragma unroll
        for (int j = 0; j < 4; j++) acc[i][j] = 0.0f;

    for (int k0 = 0; k0 < K; k0 += BK) {
#pragma unroll
        for (int f = 0; f < 2; f++) {
            const int fid = tid + f * 256;
            const int row = fid >> 3;
            const int t4  = fid & 7;
            const int mp  = row ^ ((t4 & 3) << 3);
            {
                const float4 v = *(const float4*)(A + (size_t)(m0 + row) * K + k0 + t4 * 4);
                As[t4 * 4 + 0][mp] = v.x; As[t4 * 4 + 1][mp] = v.y;
                As[t4 * 4 + 2][mp] = v.z; As[t4 * 4 + 3][mp] = v.w;
            }
            {
                const float4 v = *(const float4*)(Bm + (size_t)(n0 + row) * K + k0 + t4 * 4);
                Bs[t4 * 4 + 0][mp] = v.x; Bs[t4 * 4 + 1][mp] = v.y;
                Bs[t4 * 4 + 2][mp] = v.z; Bs[t4 * 4 + 3][mp] = v.w;
            }
        }
        __syncthreads();
#pragma unroll
        for (int kk = 0; kk < BK; kk++) {
            const int s = ((kk >> 2) & 3) << 3;
            const float4 a0 = *(const float4*)&As[kk][(ty * 4) ^ s];
            const float4 b0 = *(const float4*)&Bs[kk][(tx * 4) ^ s];
            const float av[4] = {a0.x, a0.y, a0.z, a0.w};
            const float bv[4] = {b0.x, b0.y, b0.z, b0.w};
#pragma unroll
            for (int i = 0; i < 4; i++)
#pragma unroll
                for (int j = 0; j < 4; j++)
                    acc[i][j] = fmaf(av[i], bv[j], acc[i][j]);
        }
        __syncthreads();
    }

#pragma unroll
    for (int i = 0; i < 4; i++) {
        const size_t rowoff = (size_t)(m0 + ty * 4 + i) * N;
        const int gn = n0 + tx * 4;
        const float4 bb = *(const float4*)(bias + gn);
        float4 v;
        v.x = acc[i][0] + bb.x; v.y = acc[i][1] + bb.y;
        v.z = acc[i][2] + bb.z; v.w = acc[i][3] + bb.w;
        *(float4*)(C + rowoff + gn) = v;
    }
}

// ---------------- output projection: act = tanh(x @ Wout.T + bout), fp16 MFMA ----------
// Multi-tile pipelined block (fixes R7's serial-phase HBM idle): grid 512, each block
// walks n-tiles t, t+512, ... with double-buffered 32 KB fp16 W panels. Per iteration:
//   1. issue next tile's W reads -> regs (in flight under compute)     [T14 issue-early]
//   2. K-loop on Wbuf[cur]: 8t x {4 X-loads, 4 ds_read_b128, 16 MFMA}, no barriers/cvt
//   3. barrier; cvt+swizzled ds_write next tile -> Wbuf[cur^1]         [T14 write-late]
//   4. C-epilogue through just-freed Wbuf[cur] (4x128-row transpose passes,
//      256B-contiguous stores)  -> write stream fills this phase
// Swizzle (R8-verified): 16B slot s of row r at phys (s&24)|((s^r)&7), same XOR both
// sides; all LDS ops conflict-free. mfma(A=W, B=X): D row((lane>>4)*4+reg)=n,
// col(lane&15)=m (r1-r8 verified). launch_bounds(512,3): 170-reg cap, NO spill
// (R8 lesson: (512,8) forced 64-reg cap -> acc spill -> 554 MB scratch traffic).
__global__ __launch_bounds__(512, 3)
void k_out_mfma(const _Float16* __restrict__ Xh,  // (512,256) fp16
                const float* __restrict__ W,      // (NI,256) fp32
                const float* __restrict__ bout,   // (NI)
                float* __restrict__ C)            // (512,NI)
{
    __shared__ __align__(16) _Float16 Wbuf[2][64 * 256];   // 2 x 32 KB

    const int tid  = threadIdx.x;
    const int w    = tid >> 6;                 // wave 0..7 -> m rows [w*64, w*64+64)
    const int lane = tid & 63;
    const int lr   = lane & 15;
    const int lg   = lane >> 4;                // 0..3
    const int myp  = w >> 1;                   // epilogue pass owning this wave's rows

    const _Float16* xbase = Xh + (size_t)(w * 64 + lr) * NH + lg * 8;

    float4 stg[8];

    // ---- issue global W reads for tile ny (1 KB-contiguous per wave-instr) ----
    auto issue_load = [&](int ny) {
        const int base = ny * 64;
#pragma unroll
        for (int it = 0; it < 8; ++it) {
            const int fid = it * 512 + tid;    // fp32 16B-chunk id 0..4095
            const int row = fid >> 6;          // 0..63
            const int c32 = fid & 63;
            int gr = base + row; if (gr >= NI) gr = NI - 1;
            stg[it] = *(const float4*)(W + (size_t)gr * NH + c32 * 4);
        }
    };
    // ---- cvt + swizzled ds_write of staged tile into buf ----
    auto write_lds = [&](_Float16* buf) {
#pragma unroll
        for (int it = 0; it < 8; ++it) {
            const int fid = it * 512 + tid;
            const int row = fid >> 6;
            const int c32 = fid & 63;
            const int s   = c32 >> 1;                    // 16B fp16 slot 0..31
            const int ps  = (s & 24) | ((s ^ row) & 7);  // XOR swizzle
            f16x4 h;
            h[0] = (_Float16)stg[it].x; h[1] = (_Float16)stg[it].y;
            h[2] = (_Float16)stg[it].z; h[3] = (_Float16)stg[it].w;
            *(f16x4*)((char*)buf + row * 512 + ps * 16 + (c32 & 1) * 8) = h;
        }
    };

    // ---- prologue: stage first tile ----
    issue_load(blockIdx.x);
    write_lds(Wbuf[0]);                         // compiler inserts vmcnt waits
    __syncthreads();
    int cur = 0;

    for (int t = blockIdx.x; t < NT; t += GRID_OUT) {
        const int n0 = t * 64;
        const bool has_next = (t + GRID_OUT) < NT;
        if (has_next) issue_load(t + GRID_OUT);          // reads fly under K-loop

        f32x4 acc[4][4];
#pragma unroll
        for (int nf = 0; nf < 4; ++nf)
#pragma unroll
            for (int mf = 0; mf < 4; ++mf) acc[nf][mf] = (f32x4){0.f, 0.f, 0.f, 0.f};

        const _Float16* buf = Wbuf[cur];
        // ---- K-loop: 8 steps, no barriers, no cvt ----
#pragma unroll
        for (int tt = 0; tt < 8; ++tt) {
            f16x8 xf[4];
#pragma unroll
            for (int mf = 0; mf < 4; ++mf)
                xf[mf] = *(const f16x8*)(xbase + mf * 16 * NH + tt * 32);
#pragma unroll
            for (int nf = 0; nf < 4; ++nf) {
                const int rl = nf * 16 + lr;                 // W-panel row 0..63
                const int s  = tt * 4 + lg;                  // 16B slot 0..31
                const int ps = (s & 24) | ((s ^ rl) & 7);
                const f16x8 wf = *(const f16x8*)((const char*)buf + rl * 512 + ps * 16);
#pragma unroll
                for (int mf = 0; mf < 4; ++mf)
                    acc[nf][mf] = __builtin_amdgcn_mfma_f32_16x16x32_f16(
                        wf, xf[mf], acc[nf][mf], 0, 0, 0);
            }
        }

        __syncthreads();                        // all reads of Wbuf[cur] done
        if (has_next) write_lds(Wbuf[cur ^ 1]); // stage next tile (other buffer)

        // ---- epilogue: 4 passes x 128 rows via freed Wbuf[cur]; 256B-contig stores ----
        float* Cs = (float*)Wbuf[cur];          // (128 rows x 64 cols) fp32
#pragma unroll
        for (int p = 0; p < 4; ++p) {
            if (myp == p) {
#pragma unroll
                for (int nf = 0; nf < 4; ++nf) {
                    const int gn = n0 + nf * 16 + lg * 4;
                    const float4 bb = (gn < NI) ? *(const float4*)(bout + gn)
                                                : make_float4(0.f, 0.f, 0.f, 0.f);
#pragma unroll
                    for (int mf = 0; mf < 4; ++mf) {
                        const int lrow = (w & 1) * 64 + mf * 16 + lr;   // 0..127
                        const int q    = nf * 4 + lg;                   // float4 slot
                        const int pq   = (q & 8) | ((q ^ lrow) & 7);
                        float4 v;
                        v.x = tanh_fast(acc[nf][mf][0] + bb.x);
                        v.y = tanh_fast(acc[nf][mf][1] + bb.y);
                        v.z = tanh_fast(acc[nf][mf][2] + bb.z);
                        v.w = tanh_fast(acc[nf][mf][3] + bb.w);
                        *(float4*)(Cs + lrow * 64 + pq * 4) = v;
                    }
                }
            }
            __syncthreads();
#pragma unroll
            for (int it = 0; it < 4; ++it) {
                const int fid = it * 512 + tid;     // 0..2047
                const int row = fid >> 4;           // 0..127
                const int q   = fid & 15;
                const int pq  = (q & 8) | ((q ^ row) & 7);
                const int gn  = n0 + q * 4;
                if (gn < NI) {
                    const f32x4 v = *(const f32x4*)(Cs + row * 64 + pq * 4);
                    *(f32x4*)(C + (size_t)(p * 128 + row) * NI + gn) = v;
                }
            }
            __syncthreads();                    // Cs free for next pass / next ds_write
        }
        cur ^= 1;
    }
}

extern "C" void kernel_launch(void* const* d_in, const int* in_sizes, int n_in,
                              void* d_out, int out_size, void* d_ws, size_t ws_size,
                              hipStream_t stream)
{
    const int*   idx    = (const int*)  d_in[0];
    const float* hidden = (const float*)d_in[1];   // (3,512,256)
    const float* Wih0   = (const float*)d_in[2];   // (768,100000)
    const float* WihHi  = (const float*)d_in[3];   // (2,768,256)
    const float* Whh    = (const float*)d_in[4];   // (3,768,256)
    const float* bih    = (const float*)d_in[5];   // (3,768)
    const float* bhh    = (const float*)d_in[6];   // (3,768)
    const float* Wout   = (const float*)d_in[7];   // (100000,256)
    const float* bout   = (const float*)d_in[8];   // (100000)

    float* act  = (float*)d_out;                  // (512, NI)
    float* hnew = act + (size_t)NB * NI;          // (3,512,256)
    // fp32 scratch lives in the activation region; final GEMM overwrites it.
    float* hp = act;                              // (3,512,768)
    float* xp = act + 3 * NB * H3;                // (512,768)
    // fp16 X lives in d_ws (must survive while the big GEMM writes act)
    _Float16* Xh = (_Float16*)d_ws;               // (512,256) = 256 KB

    const dim3 bs(256);
    const dim3 gs_hp(NB / 64, H3 / 64, 3);
    const dim3 gs_xp(NB / 64, H3 / 64, 1);

    // ---- all hidden-projections (depend only on input `hidden`) ----
    k_gemm_small<<<gs_hp, bs, 0, stream>>>(hidden, Whh, bhh, hp,
                                           NB, H3, NH, NB * NH, H3 * NH, H3, NB * H3);
    // ---- layer 0 (x_proj gathered inline) ----
    k_gates0<<<NB, bs, 0, stream>>>(idx, Wih0, bih, hp, hidden, hnew);
    // ---- layer 1 ----
    k_gemm_small<<<gs_xp, bs, 0, stream>>>(hnew, WihHi, bih + H3, xp,
                                           NB, H3, NH, 0, 0, 0, 0);
    k_gates<<<NB, bs, 0, stream>>>(xp, hp + NB * H3, hidden + NB * NH, hnew + NB * NH);
    // ---- layer 2 (also emits fp16 h2) ----
    k_gemm_small<<<gs_xp, bs, 0, stream>>>(hnew + NB * NH, WihHi + H3 * NH, bih + 2 * H3, xp,
                                           NB, H3, NH, 0, 0, 0, 0);
    k_gates_last<<<NB, bs, 0, stream>>>(xp, hp + 2 * NB * H3, hidden + 2 * NB * NH,
                                        hnew + 2 * NB * NH, Xh);

    // ---- output projection: 512 pipelined blocks x ~3 tiles each ----
    k_out_mfma<<<dim3(GRID_OUT), dim3(512), 0, stream>>>(Xh, Wout, bout, act);
}

// Round 10
// 242.096 us; speedup vs baseline: 2.1765x; 1.2737x over previous
//
#include <hip/hip_runtime.h>
#include <math.h>
#include <stdint.h>

#define NI 100000   // N_ITEMS
#define NB 512      // batch
#define NH 256      // hidden H
#define H3 768      // 3*H
#define NT 1563     // ceil(NI/64) n-tiles
#define GRID_OUT 512

typedef _Float16 f16x8 __attribute__((ext_vector_type(8)));
typedef _Float16 f16x4 __attribute__((ext_vector_type(4)));
typedef float    f32x4 __attribute__((ext_vector_type(4)));

__device__ __forceinline__ float tanh_fast(float x) {
    x = fminf(fmaxf(x, -9.0f), 9.0f);
    const float e = __expf(2.0f * x);
    return (e - 1.0f) * __builtin_amdgcn_rcpf(e + 1.0f);
}

// ---------------- GRU gate elementwise (layer 0: gather x_proj inline) ----------------
__global__ void k_gates0(const int* __restrict__ idx,
                         const float* __restrict__ Wih0,   // (768, NI)
                         const float* __restrict__ bih0,   // (768)
                         const float* __restrict__ hp,     // (512,768)
                         const float* __restrict__ hprev,  // (512,256)
                         float* __restrict__ hnew)         // (512,256)
{
    const int b = blockIdx.x;
    const int j = threadIdx.x;          // 0..255
    const int ib = idx[b];
    const float xr = Wih0[(size_t)(j          ) * NI + ib] + bih0[j];
    const float xz = Wih0[(size_t)(j + NH     ) * NI + ib] + bih0[j + NH];
    const float xn = Wih0[(size_t)(j + 2 * NH ) * NI + ib] + bih0[j + 2 * NH];
    const float hr = hp[b * H3 + j];
    const float hz = hp[b * H3 + NH + j];
    const float hn = hp[b * H3 + 2 * NH + j];
    const float h  = hprev[b * NH + j];
    const float r = 1.0f / (1.0f + expf(-(xr + hr)));
    const float z = 1.0f / (1.0f + expf(-(xz + hz)));
    const float n = tanhf(xn + r * hn);
    hnew[b * NH + j] = (1.0f - z) * n + z * h;
}

// ---------------- GRU gate elementwise (layer 1) ----------------
__global__ void k_gates(const float* __restrict__ xp,
                        const float* __restrict__ hp,
                        const float* __restrict__ hprev,
                        float* __restrict__ hnew)
{
    const int b = blockIdx.x;
    const int j = threadIdx.x;
    const float xr = xp[b * H3 + j];
    const float xz = xp[b * H3 + NH + j];
    const float xn = xp[b * H3 + 2 * NH + j];
    const float hr = hp[b * H3 + j];
    const float hz = hp[b * H3 + NH + j];
    const float hn = hp[b * H3 + 2 * NH + j];
    const float h  = hprev[b * NH + j];
    const float r = 1.0f / (1.0f + expf(-(xr + hr)));
    const float z = 1.0f / (1.0f + expf(-(xz + hz)));
    const float n = tanhf(xn + r * hn);
    hnew[b * NH + j] = (1.0f - z) * n + z * h;
}

// ---------------- layer 2 gates: also emit fp16 copy of h2 for the MFMA GEMM --------
__global__ void k_gates_last(const float* __restrict__ xp,
                             const float* __restrict__ hp,
                             const float* __restrict__ hprev,
                             float* __restrict__ hnew,
                             _Float16* __restrict__ Xh)    // (512,256) fp16
{
    const int b = blockIdx.x;
    const int j = threadIdx.x;
    const float xr = xp[b * H3 + j];
    const float xz = xp[b * H3 + NH + j];
    const float xn = xp[b * H3 + 2 * NH + j];
    const float hr = hp[b * H3 + j];
    const float hz = hp[b * H3 + NH + j];
    const float hn = hp[b * H3 + 2 * NH + j];
    const float h  = hprev[b * NH + j];
    const float r = 1.0f / (1.0f + expf(-(xr + hr)));
    const float z = 1.0f / (1.0f + expf(-(xz + hz)));
    const float n = tanhf(xn + r * hn);
    const float v = (1.0f - z) * n + z * h;
    hnew[b * NH + j] = v;
    Xh[b * NH + j] = (_Float16)v;
}

// ---------------- small tiled fp32 GEMM:  C = A @ B.T + bias (z-batched) ----------------
__global__ __launch_bounds__(256)
void k_gemm_small(const float* __restrict__ A0,
                  const float* __restrict__ B0,
                  const float* __restrict__ bias0,
                  float* __restrict__ C0,
                  int M, int N, int K,
                  int sA, int sB, int sBias, int sC)
{
    constexpr int BM = 64, BN = 64, BK = 32;
    __shared__ float As[BK][BM];
    __shared__ float Bs[BK][BN];

    const float* A    = A0 + (size_t)blockIdx.z * sA;
    const float* Bm   = B0 + (size_t)blockIdx.z * sB;
    const float* bias = bias0 + (size_t)blockIdx.z * sBias;
    float*       C    = C0 + (size_t)blockIdx.z * sC;

    const int tid = threadIdx.x;
    const int tx  = tid & 15;
    const int ty  = tid >> 4;
    const int m0  = blockIdx.x * BM;
    const int n0  = blockIdx.y * BN;

    float acc[4][4];
#pragma unroll
    for (int i = 0; i < 4; i++)
#pragma unroll
        for (int j = 0; j < 4; j++) acc[i][j] = 0.0f;

    for (int k0 = 0; k0 < K; k0 += BK) {
#pragma unroll
        for (int f = 0; f < 2; f++) {
            const int fid = tid + f * 256;
            const int row = fid >> 3;
            const int t4  = fid & 7;
            const int mp  = row ^ ((t4 & 3) << 3);
            {
                const float4 v = *(const float4*)(A + (size_t)(m0 + row) * K + k0 + t4 * 4);
                As[t4 * 4 + 0][mp] = v.x; As[t4 * 4 + 1][mp] = v.y;
                As[t4 * 4 + 2][mp] = v.z; As[t4 * 4 + 3][mp] = v.w;
            }
            {
                const float4 v = *(const float4*)(Bm + (size_t)(n0 + row) * K + k0 + t4 * 4);
                Bs[t4 * 4 + 0][mp] = v.x; Bs[t4 * 4 + 1][mp] = v.y;
                Bs[t4 * 4 + 2][mp] = v.z; Bs[t4 * 4 + 3][mp] = v.w;
            }
        }
        __syncthreads();
#pragma unroll
        for (int kk = 0; kk < BK; kk++) {
            const int s = ((kk >> 2) & 3) << 3;
            const float4 a0 = *(const float4*)&As[kk][(ty * 4) ^ s];
            const float4 b0 = *(const float4*)&Bs[kk][(tx * 4) ^ s];
            const float av[4] = {a0.x, a0.y, a0.z, a0.w};
            const float bv[4] = {b0.x, b0.y, b0.z, b0.w};
#pragma unroll
            for (int i = 0; i < 4; i++)
#pragma unroll
                for (int j = 0; j < 4; j++)
                    acc[i][j] = fmaf(av[i], bv[j], acc[i][j]);
        }
        __syncthreads();
    }

#pragma unroll
    for (int i = 0; i < 4; i++) {
        const size_t rowoff = (size_t)(m0 + ty * 4 + i) * N;
        const int gn = n0 + tx * 4;
        const float4 bb = *(const float4*)(bias + gn);
        float4 v;
        v.x = acc[i][0] + bb.x; v.y = acc[i][1] + bb.y;
        v.z = acc[i][2] + bb.z; v.w = acc[i][3] + bb.w;
        *(float4*)(C + rowoff + gn) = v;
    }
}

// ---------------- output projection: act = tanh(x @ Wout.T + bout), fp16 MFMA ----------
// Multi-tile pipelined block: grid 512, each block walks n-tiles t, t+512, ... with
// double-buffered 32 KB fp16 W panels. Per iteration:
//   1. issue next tile's W reads -> regs (in flight under compute)     [T14 issue-early]
//   2. K-loop on Wbuf[cur]: 8t x {4 X-loads, 4 ds_read_b128, 16 MFMA}, no barriers/cvt
//   3. barrier; cvt+swizzled ds_write next tile -> Wbuf[cur^1]         [T14 write-late]
//   4. C-epilogue through just-freed Wbuf[cur] (4x128-row transpose passes,
//      256B-contiguous stores)
// Swizzle (R8-verified): 16B slot s of row r at phys (s&24)|((s^r)&7), same XOR both
// sides. mfma(A=W, B=X): D row((lane>>4)*4+reg)=n, col(lane&15)=m (r1-r9 verified).
// launch_bounds(512,2): 8-wave block = 2 waves/EU = 1 block/CU -> 256-reg cap.
// R9 LESSON: (512,3) forced 2 blocks/CU -> 128-reg cap -> acc/stg spill -> +180 MB
// FETCH / +228 MB WRITE scratch traffic (VGPR_Count=84 vs ~150 needed). Occupancy
// units are per-EU waves in block-granularity steps — min-waves arg must match.
__global__ __launch_bounds__(512, 2)
void k_out_mfma(const _Float16* __restrict__ Xh,  // (512,256) fp16
                const float* __restrict__ W,      // (NI,256) fp32
                const float* __restrict__ bout,   // (NI)
                float* __restrict__ C)            // (512,NI)
{
    __shared__ __align__(16) _Float16 Wbuf[2][64 * 256];   // 2 x 32 KB

    const int tid  = threadIdx.x;
    const int w    = tid >> 6;                 // wave 0..7 -> m rows [w*64, w*64+64)
    const int lane = tid & 63;
    const int lr   = lane & 15;
    const int lg   = lane >> 4;                // 0..3
    const int myp  = w >> 1;                   // epilogue pass owning this wave's rows

    const _Float16* xbase = Xh + (size_t)(w * 64 + lr) * NH + lg * 8;

    float4 stg[8];

    // ---- issue global W reads for tile ny (1 KB-contiguous per wave-instr) ----
    auto issue_load = [&](int ny) {
        const int base = ny * 64;
#pragma unroll
        for (int it = 0; it < 8; ++it) {
            const int fid = it * 512 + tid;    // fp32 16B-chunk id 0..4095
            const int row = fid >> 6;          // 0..63
            const int c32 = fid & 63;
            int gr = base + row; if (gr >= NI) gr = NI - 1;
            stg[it] = *(const float4*)(W + (size_t)gr * NH + c32 * 4);
        }
    };
    // ---- cvt + swizzled ds_write of staged tile into buf ----
    auto write_lds = [&](_Float16* buf) {
#pragma unroll
        for (int it = 0; it < 8; ++it) {
            const int fid = it * 512 + tid;
            const int row = fid >> 6;
            const int c32 = fid & 63;
            const int s   = c32 >> 1;                    // 16B fp16 slot 0..31
            const int ps  = (s & 24) | ((s ^ row) & 7);  // XOR swizzle
            f16x4 h;
            h[0] = (_Float16)stg[it].x; h[1] = (_Float16)stg[it].y;
            h[2] = (_Float16)stg[it].z; h[3] = (_Float16)stg[it].w;
            *(f16x4*)((char*)buf + row * 512 + ps * 16 + (c32 & 1) * 8) = h;
        }
    };

    // ---- prologue: stage first tile ----
    issue_load(blockIdx.x);
    write_lds(Wbuf[0]);                         // compiler inserts vmcnt waits
    __syncthreads();
    int cur = 0;

    for (int t = blockIdx.x; t < NT; t += GRID_OUT) {
        const int n0 = t * 64;
        const bool has_next = (t + GRID_OUT) < NT;
        if (has_next) issue_load(t + GRID_OUT);          // reads fly under K-loop

        f32x4 acc[4][4];
#pragma unroll
        for (int nf = 0; nf < 4; ++nf)
#pragma unroll
            for (int mf = 0; mf < 4; ++mf) acc[nf][mf] = (f32x4){0.f, 0.f, 0.f, 0.f};

        const _Float16* buf = Wbuf[cur];
        // ---- K-loop: 8 steps, no barriers, no cvt ----
#pragma unroll
        for (int tt = 0; tt < 8; ++tt) {
            f16x8 xf[4];
#pragma unroll
            for (int mf = 0; mf < 4; ++mf)
                xf[mf] = *(const f16x8*)(xbase + mf * 16 * NH + tt * 32);
#pragma unroll
            for (int nf = 0; nf < 4; ++nf) {
                const int rl = nf * 16 + lr;                 // W-panel row 0..63
                const int s  = tt * 4 + lg;                  // 16B slot 0..31
                const int ps = (s & 24) | ((s ^ rl) & 7);
                const f16x8 wf = *(const f16x8*)((const char*)buf + rl * 512 + ps * 16);
#pragma unroll
                for (int mf = 0; mf < 4; ++mf)
                    acc[nf][mf] = __builtin_amdgcn_mfma_f32_16x16x32_f16(
                        wf, xf[mf], acc[nf][mf], 0, 0, 0);
            }
        }

        __syncthreads();                        // all reads of Wbuf[cur] done
        if (has_next) write_lds(Wbuf[cur ^ 1]); // stage next tile (other buffer)

        // ---- epilogue: 4 passes x 128 rows via freed Wbuf[cur]; 256B-contig stores ----
        float* Cs = (float*)Wbuf[cur];          // (128 rows x 64 cols) fp32
#pragma unroll
        for (int p = 0; p < 4; ++p) {
            if (myp == p) {
#pragma unroll
                for (int nf = 0; nf < 4; ++nf) {
                    const int gn = n0 + nf * 16 + lg * 4;
                    const float4 bb = (gn < NI) ? *(const float4*)(bout + gn)
                                                : make_float4(0.f, 0.f, 0.f, 0.f);
#pragma unroll
                    for (int mf = 0; mf < 4; ++mf) {
                        const int lrow = (w & 1) * 64 + mf * 16 + lr;   // 0..127
                        const int q    = nf * 4 + lg;                   // float4 slot
                        const int pq   = (q & 8) | ((q ^ lrow) & 7);
                        float4 v;
                        v.x = tanh_fast(acc[nf][mf][0] + bb.x);
                        v.y = tanh_fast(acc[nf][mf][1] + bb.y);
                        v.z = tanh_fast(acc[nf][mf][2] + bb.z);
                        v.w = tanh_fast(acc[nf][mf][3] + bb.w);
                        *(float4*)(Cs + lrow * 64 + pq * 4) = v;
                    }
                }
            }
            __syncthreads();
#pragma unroll
            for (int it = 0; it < 4; ++it) {
                const int fid = it * 512 + tid;     // 0..2047
                const int row = fid >> 4;           // 0..127
                const int q   = fid & 15;
                const int pq  = (q & 8) | ((q ^ row) & 7);
                const int gn  = n0 + q * 4;
                if (gn < NI) {
                    const f32x4 v = *(const f32x4*)(Cs + row * 64 + pq * 4);
                    *(f32x4*)(C + (size_t)(p * 128 + row) * NI + gn) = v;
                }
            }
            __syncthreads();                    // Cs free for next pass / next ds_write
        }
        cur ^= 1;
    }
}

extern "C" void kernel_launch(void* const* d_in, const int* in_sizes, int n_in,
                              void* d_out, int out_size, void* d_ws, size_t ws_size,
                              hipStream_t stream)
{
    const int*   idx    = (const int*)  d_in[0];
    const float* hidden = (const float*)d_in[1];   // (3,512,256)
    const float* Wih0   = (const float*)d_in[2];   // (768,100000)
    const float* WihHi  = (const float*)d_in[3];   // (2,768,256)
    const float* Whh    = (const float*)d_in[4];   // (3,768,256)
    const float* bih    = (const float*)d_in[5];   // (3,768)
    const float* bhh    = (const float*)d_in[6];   // (3,768)
    const float* Wout   = (const float*)d_in[7];   // (100000,256)
    const float* bout   = (const float*)d_in[8];   // (100000)

    float* act  = (float*)d_out;                  // (512, NI)
    float* hnew = act + (size_t)NB * NI;          // (3,512,256)
    // fp32 scratch lives in the activation region; final GEMM overwrites it.
    float* hp = act;                              // (3,512,768)
    float* xp = act + 3 * NB * H3;                // (512,768)
    // fp16 X lives in d_ws (must survive while the big GEMM writes act)
    _Float16* Xh = (_Float16*)d_ws;               // (512,256) = 256 KB

    const dim3 bs(256);
    const dim3 gs_hp(NB / 64, H3 / 64, 3);
    const dim3 gs_xp(NB / 64, H3 / 64, 1);

    // ---- all hidden-projections (depend only on input `hidden`) ----
    k_gemm_small<<<gs_hp, bs, 0, stream>>>(hidden, Whh, bhh, hp,
                                           NB, H3, NH, NB * NH, H3 * NH, H3, NB * H3);
    // ---- layer 0 (x_proj gathered inline) ----
    k_gates0<<<NB, bs, 0, stream>>>(idx, Wih0, bih, hp, hidden, hnew);
    // ---- layer 1 ----
    k_gemm_small<<<gs_xp, bs, 0, stream>>>(hnew, WihHi, bih + H3, xp,
                                           NB, H3, NH, 0, 0, 0, 0);
    k_gates<<<NB, bs, 0, stream>>>(xp, hp + NB * H3, hidden + NB * NH, hnew + NB * NH);
    // ---- layer 2 (also emits fp16 h2) ----
    k_gemm_small<<<gs_xp, bs, 0, stream>>>(hnew + NB * NH, WihHi + H3 * NH, bih + 2 * H3, xp,
                                           NB, H3, NH, 0, 0, 0, 0);
    k_gates_last<<<NB, bs, 0, stream>>>(xp, hp + 2 * NB * H3, hidden + 2 * NB * NH,
                                        hnew + 2 * NB * NH, Xh);

    // ---- output projection: 512 pipelined blocks x ~3 tiles each ----
    k_out_mfma<<<dim3(GRID_OUT), dim3(512), 0, stream>>>(Xh, Wout, bout, act);
}